// Round 1
// baseline (14089.684 us; speedup 1.0000x reference)
//
#include <hip/hip_runtime.h>
#include <hip/hip_bf16.h>

// dims
#define NTOK_TOTAL 401408   // B*D*H*W = 8*16*56*56
#define NWIN_TOTAL 4096     // B * NW
#define N_TOK 98
#define C_DIM 96

// ---------------- Kernel 1: LN1 + cyclic shift + window partition ----------------
// bufh[w*98*96 + t*96 + c] = LN(x)[b, (dq*2+td+1)%16, (hq*7+th+3)%56, (wq*7+tw+3)%56, c]
__global__ __launch_bounds__(256) void k_ln1(const float* __restrict__ x,
                                             const float* __restrict__ g1,
                                             const float* __restrict__ b1,
                                             float* __restrict__ bufh) {
    int tid = threadIdx.x;
    int lane = tid & 31;
    int sub = tid >> 5;
    int g = blockIdx.x * 8 + sub;            // global (window,token) id, 0..401407
    int w = g / 98;
    int t = g - w * 98;
    int b = w >> 9;
    int nw = w & 511;
    int dq = nw >> 6, hq = (nw >> 3) & 7, wq = nw & 7;
    int td = t / 49; int r = t - td * 49; int th = r / 7; int tw = r - th * 7;
    int gd = (dq * 2 + td + 1) & 15;
    int gh = hq * 7 + th + 3; if (gh >= 56) gh -= 56;
    int gw = wq * 7 + tw + 3; if (gw >= 56) gw -= 56;
    const float* row = x + (size_t)(((b * 16 + gd) * 56 + gh) * 56 + gw) * 96;
    float v0 = row[lane], v1 = row[lane + 32], v2 = row[lane + 64];
    float s = v0 + v1 + v2;
    float s2 = v0 * v0 + v1 * v1 + v2 * v2;
    #pragma unroll
    for (int off = 16; off >= 1; off >>= 1) {
        s  += __shfl_xor(s,  off, 32);
        s2 += __shfl_xor(s2, off, 32);
    }
    float mu = s * (1.0f / 96.0f);
    float var = s2 * (1.0f / 96.0f) - mu * mu;
    float rs = rsqrtf(var + 1e-5f);
    float* orow = bufh + (size_t)g * 96;
    orow[lane]      = (v0 - mu) * rs * g1[lane]      + b1[lane];
    orow[lane + 32] = (v1 - mu) * rs * g1[lane + 32] + b1[lane + 32];
    orow[lane + 64] = (v2 - mu) * rs * g1[lane + 64] + b1[lane + 64];
}

// ---------------- Kernel 2: per-window attention + proj + residual scatter ----------------
__global__ __launch_bounds__(256) void k_attn(const float* __restrict__ bufh,
                                              const float* __restrict__ x,
                                              const float* __restrict__ mask,
                                              const float* __restrict__ w_qkv,
                                              const float* __restrict__ b_qkv,
                                              const float* __restrict__ w_proj,
                                              const float* __restrict__ b_proj,
                                              const float* __restrict__ btab,
                                              const int* __restrict__ relidx,
                                              float* __restrict__ xout) {
    __shared__ float xw[98][97];   // input window tokens (padded stride: 96 % 32 == 0!)
    __shared__ float qs[98][33];
    __shared__ float ks[98][33];
    __shared__ float vs[98][33];
    __shared__ float ss[98][99];
    __shared__ float os[98][97];
    int tid = threadIdx.x;
    int w = blockIdx.x;
    int nw = w & 511;
    const float* hw = bufh + (size_t)w * (98 * 96);
    for (int e = tid; e < 98 * 96; e += 256) {
        int t = e / 96, c = e - t * 96;
        xw[t][c] = hw[e];
    }
    __syncthreads();
    for (int h = 0; h < 3; ++h) {
        // QKV for this head: q/k/v [98][32]
        for (int e = tid; e < 3 * 98 * 32; e += 256) {
            int sel = e / 3136;
            int r = e - sel * 3136;
            int t = r >> 5, hd = r & 31;
            int col = sel * 96 + h * 32 + hd;
            const float* wc = w_qkv + col;
            float a0 = 0.f, a1 = 0.f, a2 = 0.f, a3 = 0.f;
            #pragma unroll
            for (int c = 0; c < 96; c += 4) {
                a0 += xw[t][c]     * wc[(c)     * 288];
                a1 += xw[t][c + 1] * wc[(c + 1) * 288];
                a2 += xw[t][c + 2] * wc[(c + 2) * 288];
                a3 += xw[t][c + 3] * wc[(c + 3) * 288];
            }
            float acc = (a0 + a1) + (a2 + a3) + b_qkv[col];
            if (sel == 0) acc *= 0.17677669529663687f;   // HD^-0.5
            float (*dst)[33] = (sel == 0) ? qs : (sel == 1) ? ks : vs;
            dst[t][hd] = acc;
        }
        __syncthreads();
        // S = q @ k^T + bias + mask
        for (int e = tid; e < 98 * 98; e += 256) {
            int i = e / 98, j = e - i * 98;
            float a0 = 0.f, a1 = 0.f, a2 = 0.f, a3 = 0.f;
            #pragma unroll
            for (int d = 0; d < 32; d += 4) {
                a0 += qs[i][d]     * ks[j][d];
                a1 += qs[i][d + 1] * ks[j][d + 1];
                a2 += qs[i][d + 2] * ks[j][d + 2];
                a3 += qs[i][d + 3] * ks[j][d + 3];
            }
            float acc = (a0 + a1) + (a2 + a3);
            acc += btab[relidx[e] * 3 + h];
            acc += mask[(size_t)nw * 9604 + e];
            ss[i][j] = acc;
        }
        __syncthreads();
        // softmax rows
        if (tid < 98) {
            float m = -1e30f;
            #pragma unroll 2
            for (int j = 0; j < 98; ++j) m = fmaxf(m, ss[tid][j]);
            float sum = 0.f;
            #pragma unroll 2
            for (int j = 0; j < 98; ++j) {
                float p = __expf(ss[tid][j] - m);
                ss[tid][j] = p;
                sum += p;
            }
            float inv = 1.0f / sum;
            #pragma unroll 2
            for (int j = 0; j < 98; ++j) ss[tid][j] *= inv;
        }
        __syncthreads();
        // O_h = S @ V
        for (int e = tid; e < 98 * 32; e += 256) {
            int t = e >> 5, hd = e & 31;
            float a0 = 0.f, a1 = 0.f;
            #pragma unroll
            for (int j = 0; j < 98; j += 2) {
                a0 += ss[t][j]     * vs[j][hd];
                a1 += ss[t][j + 1] * vs[j + 1][hd];
            }
            os[t][h * 32 + hd] = a0 + a1;
        }
        __syncthreads();
    }
    // proj + shortcut + scatter back (output coord == input gather coord)
    int b = w >> 9;
    int dq = (w >> 6) & 7, hq = (w >> 3) & 7, wq = w & 7;
    for (int e = tid; e < 98 * 96; e += 256) {
        int t = e / 96, c = e - t * 96;
        const float* wp = w_proj + c;
        float a0 = 0.f, a1 = 0.f, a2 = 0.f, a3 = 0.f;
        #pragma unroll
        for (int c2 = 0; c2 < 96; c2 += 4) {
            a0 += os[t][c2]     * wp[(c2)     * 96];
            a1 += os[t][c2 + 1] * wp[(c2 + 1) * 96];
            a2 += os[t][c2 + 2] * wp[(c2 + 2) * 96];
            a3 += os[t][c2 + 3] * wp[(c2 + 3) * 96];
        }
        float acc = (a0 + a1) + (a2 + a3) + b_proj[c];
        int td = t / 49; int r = t - td * 49; int th = r / 7; int tw = r - th * 7;
        int gd = (dq * 2 + td + 1) & 15;
        int gh = hq * 7 + th + 3; if (gh >= 56) gh -= 56;
        int gw = wq * 7 + tw + 3; if (gw >= 56) gw -= 56;
        size_t gi = (size_t)(((b * 16 + gd) * 56 + gh) * 56 + gw) * 96 + c;
        xout[gi] = x[gi] + acc;
    }
}

// ---------------- Kernel 3: LN2 + FC1 + GELU + FC2 + residual (in-place on d_out) ----------------
__global__ __launch_bounds__(256) void k_mlp(const float* __restrict__ g2,
                                             const float* __restrict__ b2,
                                             const float* __restrict__ w1,
                                             const float* __restrict__ b1f,
                                             const float* __restrict__ w2,
                                             const float* __restrict__ b2f,
                                             float* __restrict__ xio) {
    __shared__ float h2s[8][96];
    __shared__ float ys[8][384];
    int tid = threadIdx.x;
    int lane = tid & 31, sub = tid >> 5;
    size_t g = (size_t)blockIdx.x * 8 + sub;
    float* row = xio + g * 96;
    float v0 = row[lane], v1 = row[lane + 32], v2 = row[lane + 64];
    float s = v0 + v1 + v2, s2 = v0 * v0 + v1 * v1 + v2 * v2;
    #pragma unroll
    for (int off = 16; off >= 1; off >>= 1) {
        s  += __shfl_xor(s,  off, 32);
        s2 += __shfl_xor(s2, off, 32);
    }
    float mu = s * (1.f / 96.f), var = s2 * (1.f / 96.f) - mu * mu;
    float rs = rsqrtf(var + 1e-5f);
    h2s[sub][lane]      = (v0 - mu) * rs * g2[lane]      + b2[lane];
    h2s[sub][lane + 32] = (v1 - mu) * rs * g2[lane + 32] + b2[lane + 32];
    h2s[sub][lane + 64] = (v2 - mu) * rs * g2[lane + 64] + b2[lane + 64];
    __syncthreads();
    // FC1 + exact GELU
    for (int k = 0; k < 12; k += 2) {
        int j0 = k * 32 + lane, j1 = j0 + 32;
        float a0 = b1f[j0], a1 = b1f[j1];
        #pragma unroll 8
        for (int c = 0; c < 96; ++c) {
            float hv = h2s[sub][c];
            a0 += hv * w1[c * 384 + j0];
            a1 += hv * w1[c * 384 + j1];
        }
        ys[sub][j0] = 0.5f * a0 * (1.f + erff(a0 * 0.70710678118654752f));
        ys[sub][j1] = 0.5f * a1 * (1.f + erff(a1 * 0.70710678118654752f));
    }
    __syncthreads();
    // FC2 + residual
    float o0 = b2f[lane], o1 = b2f[lane + 32], o2 = b2f[lane + 64];
    #pragma unroll 4
    for (int j = 0; j < 384; ++j) {
        float yv = ys[sub][j];
        o0 += yv * w2[j * 96 + lane];
        o1 += yv * w2[j * 96 + lane + 32];
        o2 += yv * w2[j * 96 + lane + 64];
    }
    row[lane]      = v0 + o0;
    row[lane + 32] = v1 + o1;
    row[lane + 64] = v2 + o2;
}

extern "C" void kernel_launch(void* const* d_in, const int* in_sizes, int n_in,
                              void* d_out, int out_size, void* d_ws, size_t ws_size,
                              hipStream_t stream) {
    const float* x      = (const float*)d_in[0];
    const float* mask   = (const float*)d_in[1];
    const float* g1     = (const float*)d_in[2];
    const float* b1     = (const float*)d_in[3];
    const float* w_qkv  = (const float*)d_in[4];
    const float* b_qkv  = (const float*)d_in[5];
    const float* w_proj = (const float*)d_in[6];
    const float* b_proj = (const float*)d_in[7];
    const float* btab   = (const float*)d_in[8];
    const int*   relidx = (const int*)d_in[9];
    const float* g2     = (const float*)d_in[10];
    const float* b2     = (const float*)d_in[11];
    const float* w_fc1  = (const float*)d_in[12];
    const float* b_fc1  = (const float*)d_in[13];
    const float* w_fc2  = (const float*)d_in[14];
    const float* b_fc2  = (const float*)d_in[15];
    float* out  = (float*)d_out;
    float* bufh = (float*)d_ws;   // 4096*98*96 fp32 = 154,140,672 bytes

    hipLaunchKernelGGL(k_ln1, dim3(NTOK_TOTAL / 8), dim3(256), 0, stream, x, g1, b1, bufh);
    hipLaunchKernelGGL(k_attn, dim3(NWIN_TOTAL), dim3(256), 0, stream,
                       bufh, x, mask, w_qkv, b_qkv, w_proj, b_proj, btab, relidx, out);
    hipLaunchKernelGGL(k_mlp, dim3(NTOK_TOTAL / 8), dim3(256), 0, stream,
                       g2, b2, w_fc1, b_fc1, w_fc2, b_fc2, out);
}

// Round 2
// 5210.143 us; speedup vs baseline: 2.7043x; 2.7043x over previous
//
#include <hip/hip_runtime.h>
#include <hip/hip_bf16.h>

#define SCALE_Q 0.17677669529663687f

static __device__ __forceinline__ float gelu_exact(float a) {
    return 0.5f * a * (1.0f + erff(a * 0.70710678118654752f));
}

// ---------------- Kernel 1: per-(window,head) attention -> obuf ----------------
// LDS floats: xw/ss [98][100] @0 (9800) | qs [98][36] @9800 (3528)
//             kst [32][100] @13328 (3200) | vs [98][33] @16528 (3234)  = 79,048 B
__global__ __launch_bounds__(256, 2) void k_attn2(
    const float* __restrict__ x,
    const float* __restrict__ mask,
    const float* __restrict__ g1v,
    const float* __restrict__ b1v,
    const float* __restrict__ w_qkv,
    const float* __restrict__ b_qkv,
    const float* __restrict__ btab,
    const int* __restrict__ relidx,
    float* __restrict__ obuf) {
    __shared__ __align__(16) float sm[19762];
    float* xw  = sm;            // [98][100], later reused as ss
    float* qs  = sm + 9800;     // [98][36]
    float* kst = sm + 13328;    // [32][100]  (K transposed: kst[d][t])
    float* vs  = sm + 16528;    // [98][33]

    const int tid  = threadIdx.x;
    const int lane = tid & 31;
    const int sub  = tid >> 5;
    const int bid  = blockIdx.x;
    const int w    = bid / 3;
    const int h    = bid - 3 * w;
    const int b    = w >> 9;
    const int nw   = w & 511;
    const int dq = nw >> 6, hq = (nw >> 3) & 7, wq = nw & 7;

    // ---- LN1 + cyclic shift + gather into xw ----
    for (int tt = 0; tt < 13; ++tt) {
        int t = sub + 8 * tt;
        if (t < 98) {
            int td = t / 49; int r = t - td * 49; int th = r / 7; int tw = r - th * 7;
            int gd = (dq * 2 + td + 1) & 15;
            int gh = hq * 7 + th + 3; if (gh >= 56) gh -= 56;
            int gw = wq * 7 + tw + 3; if (gw >= 56) gw -= 56;
            const float* row = x + (size_t)(((b * 16 + gd) * 56 + gh) * 56 + gw) * 96;
            float v0 = row[lane], v1 = row[lane + 32], v2 = row[lane + 64];
            float s = v0 + v1 + v2, s2 = v0 * v0 + v1 * v1 + v2 * v2;
            #pragma unroll
            for (int off = 16; off >= 1; off >>= 1) {
                s  += __shfl_xor(s,  off, 32);
                s2 += __shfl_xor(s2, off, 32);
            }
            float mu = s * (1.f / 96.f);
            float rs = rsqrtf(s2 * (1.f / 96.f) - mu * mu + 1e-5f);
            xw[t * 100 + lane]      = (v0 - mu) * rs * g1v[lane]      + b1v[lane];
            xw[t * 100 + lane + 32] = (v1 - mu) * rs * g1v[lane + 32] + b1v[lane + 32];
            xw[t * 100 + lane + 64] = (v2 - mu) * rs * g1v[lane + 64] + b1v[lane + 64];
        }
    }
    __syncthreads();

    // ---- QKV projection for this head: q[t][hd], kT[hd? no: kst[d][t]], v[t][hd] ----
    {
        const int colq = h * 32 + lane;            // q col in w_qkv
        const float bq = b_qkv[colq];
        const float bk = b_qkv[96 + colq];
        const float bv = b_qkv[192 + colq];
        float accq[13], acck[13], accv[13];
        #pragma unroll
        for (int tt = 0; tt < 13; ++tt) { accq[tt] = bq; acck[tt] = bk; accv[tt] = bv; }
        for (int cc = 0; cc < 24; ++cc) {
            int c = cc * 4;
            const float* wb = w_qkv + (size_t)c * 288;
            float wq0 = wb[colq],        wq1 = wb[288 + colq],        wq2 = wb[576 + colq],        wq3 = wb[864 + colq];
            float wk0 = wb[96 + colq],   wk1 = wb[288 + 96 + colq],   wk2 = wb[576 + 96 + colq],   wk3 = wb[864 + 96 + colq];
            float wv0 = wb[192 + colq],  wv1 = wb[288 + 192 + colq],  wv2 = wb[576 + 192 + colq],  wv3 = wb[864 + 192 + colq];
            #pragma unroll
            for (int tt = 0; tt < 13; ++tt) {
                int t = sub + 8 * tt;
                if (t < 98) {
                    float4 xv = *reinterpret_cast<const float4*>(&xw[t * 100 + c]);
                    accq[tt] += xv.x * wq0 + xv.y * wq1 + xv.z * wq2 + xv.w * wq3;
                    acck[tt] += xv.x * wk0 + xv.y * wk1 + xv.z * wk2 + xv.w * wk3;
                    accv[tt] += xv.x * wv0 + xv.y * wv1 + xv.z * wv2 + xv.w * wv3;
                }
            }
        }
        #pragma unroll
        for (int tt = 0; tt < 13; ++tt) {
            int t = sub + 8 * tt;
            if (t < 98) {
                qs[t * 36 + lane]   = accq[tt] * SCALE_Q;
                kst[lane * 100 + t] = acck[tt];
                vs[t * 33 + lane]   = accv[tt];
            }
        }
    }
    __syncthreads();

    // ---- S = q @ k^T + bias + mask  (outer-product over d, float4 over j) ----
    {
        const int jq = 4 * lane;  // lanes 0..24 carry valid j
        float acc[13][4];
        #pragma unroll
        for (int ii = 0; ii < 13; ++ii)
            #pragma unroll
            for (int r = 0; r < 4; ++r) acc[ii][r] = 0.f;
        #pragma unroll
        for (int dqi = 0; dqi < 8; ++dqi) {
            int d = dqi * 4;
            float4 k0 = *reinterpret_cast<const float4*>(&kst[(d + 0) * 100 + jq]);
            float4 k1 = *reinterpret_cast<const float4*>(&kst[(d + 1) * 100 + jq]);
            float4 k2 = *reinterpret_cast<const float4*>(&kst[(d + 2) * 100 + jq]);
            float4 k3 = *reinterpret_cast<const float4*>(&kst[(d + 3) * 100 + jq]);
            #pragma unroll
            for (int ii = 0; ii < 13; ++ii) {
                int i = sub + 8 * ii;
                if (i < 98) {
                    float4 qv = *reinterpret_cast<const float4*>(&qs[i * 36 + d]);
                    acc[ii][0] += qv.x * k0.x + qv.y * k1.x + qv.z * k2.x + qv.w * k3.x;
                    acc[ii][1] += qv.x * k0.y + qv.y * k1.y + qv.z * k2.y + qv.w * k3.y;
                    acc[ii][2] += qv.x * k0.z + qv.y * k1.z + qv.z * k2.z + qv.w * k3.z;
                    acc[ii][3] += qv.x * k0.w + qv.y * k1.w + qv.z * k2.w + qv.w * k3.w;
                }
            }
        }
        const float* mrow = mask + (size_t)nw * 9604;
        #pragma unroll
        for (int ii = 0; ii < 13; ++ii) {
            int i = sub + 8 * ii;
            if (i < 98) {
                #pragma unroll
                for (int r = 0; r < 4; ++r) {
                    int j = jq + r;
                    if (j < 98) {
                        int ri = relidx[i * 98 + j];
                        xw[i * 100 + j] = acc[ii][r] + btab[ri * 3 + h] + mrow[i * 98 + j];
                    }
                }
            }
        }
    }
    __syncthreads();

    // ---- softmax rows (sub owns rows i === sub mod 8; 32 lanes reduce) ----
    for (int i = sub; i < 98; i += 8) {
        float m = -1e30f;
        for (int j = lane; j < 98; j += 32) m = fmaxf(m, xw[i * 100 + j]);
        #pragma unroll
        for (int off = 16; off >= 1; off >>= 1) m = fmaxf(m, __shfl_xor(m, off, 32));
        float ssum = 0.f;
        for (int j = lane; j < 98; j += 32) {
            float p = __expf(xw[i * 100 + j] - m);
            xw[i * 100 + j] = p;
            ssum += p;
        }
        #pragma unroll
        for (int off = 16; off >= 1; off >>= 1) ssum += __shfl_xor(ssum, off, 32);
        float inv = 1.f / ssum;
        for (int j = lane; j < 98; j += 32) xw[i * 100 + j] *= inv;
    }
    __syncthreads();

    // ---- O_h = P @ V -> obuf[w][t][h*32+hd] ----
    {
        float acc2[13];
        #pragma unroll
        for (int tt = 0; tt < 13; ++tt) acc2[tt] = 0.f;
        for (int jc = 0; jc < 24; ++jc) {
            int j = jc * 4;
            float v0 = vs[(j + 0) * 33 + lane];
            float v1 = vs[(j + 1) * 33 + lane];
            float v2 = vs[(j + 2) * 33 + lane];
            float v3 = vs[(j + 3) * 33 + lane];
            #pragma unroll
            for (int tt = 0; tt < 13; ++tt) {
                int t = sub + 8 * tt;
                if (t < 98) {
                    float4 sv = *reinterpret_cast<const float4*>(&xw[t * 100 + j]);
                    acc2[tt] += sv.x * v0 + sv.y * v1 + sv.z * v2 + sv.w * v3;
                }
            }
        }
        {
            float v0 = vs[96 * 33 + lane], v1 = vs[97 * 33 + lane];
            #pragma unroll
            for (int tt = 0; tt < 13; ++tt) {
                int t = sub + 8 * tt;
                if (t < 98) acc2[tt] += xw[t * 100 + 96] * v0 + xw[t * 100 + 97] * v1;
            }
        }
        float* ob = obuf + (size_t)w * 9408 + h * 32 + lane;
        #pragma unroll
        for (int tt = 0; tt < 13; ++tt) {
            int t = sub + 8 * tt;
            if (t < 98) ob[t * 96] = acc2[tt];
        }
    }
}

// ---------------- Kernel 2: proj + shortcut + reverse-shift scatter ----------------
__global__ __launch_bounds__(256, 2) void k_proj(
    const float* __restrict__ obuf,
    const float* __restrict__ x,
    const float* __restrict__ w_proj,
    const float* __restrict__ b_proj,
    float* __restrict__ out) {
    __shared__ __align__(16) float os[9800];   // [98][100]
    const int tid = threadIdx.x, lane = tid & 31, sub = tid >> 5;
    const int w = blockIdx.x;
    const float* ow = obuf + (size_t)w * 9408;
    for (int e = tid; e < 2352; e += 256) {
        int t = e / 24, q = e - t * 24;
        *reinterpret_cast<float4*>(&os[t * 100 + q * 4]) =
            *reinterpret_cast<const float4*>(&ow[t * 96 + q * 4]);
    }
    __syncthreads();
    float a0[13], a1[13], a2[13];
    const float bp0 = b_proj[lane], bp1 = b_proj[lane + 32], bp2 = b_proj[lane + 64];
    #pragma unroll
    for (int tt = 0; tt < 13; ++tt) { a0[tt] = bp0; a1[tt] = bp1; a2[tt] = bp2; }
    for (int cc = 0; cc < 24; ++cc) {
        int c = cc * 4;
        const float* wb = w_proj + (size_t)c * 96;
        float w00 = wb[lane],      w01 = wb[96 + lane],  w02 = wb[192 + lane], w03 = wb[288 + lane];
        float w10 = wb[32 + lane], w11 = wb[128 + lane], w12 = wb[224 + lane], w13 = wb[320 + lane];
        float w20 = wb[64 + lane], w21 = wb[160 + lane], w22 = wb[256 + lane], w23 = wb[352 + lane];
        #pragma unroll
        for (int tt = 0; tt < 13; ++tt) {
            int t = sub + 8 * tt;
            if (t < 98) {
                float4 ov = *reinterpret_cast<const float4*>(&os[t * 100 + c]);
                a0[tt] += ov.x * w00 + ov.y * w01 + ov.z * w02 + ov.w * w03;
                a1[tt] += ov.x * w10 + ov.y * w11 + ov.z * w12 + ov.w * w13;
                a2[tt] += ov.x * w20 + ov.y * w21 + ov.z * w22 + ov.w * w23;
            }
        }
    }
    const int b = w >> 9, nw = w & 511;
    const int dq = nw >> 6, hq = (nw >> 3) & 7, wq = nw & 7;
    #pragma unroll
    for (int tt = 0; tt < 13; ++tt) {
        int t = sub + 8 * tt;
        if (t < 98) {
            int td = t / 49; int r = t - td * 49; int th = r / 7; int tw = r - th * 7;
            int gd = (dq * 2 + td + 1) & 15;
            int gh = hq * 7 + th + 3; if (gh >= 56) gh -= 56;
            int gw = wq * 7 + tw + 3; if (gw >= 56) gw -= 56;
            size_t base = (size_t)(((b * 16 + gd) * 56 + gh) * 56 + gw) * 96;
            out[base + lane]      = x[base + lane]      + a0[tt];
            out[base + lane + 32] = x[base + lane + 32] + a1[tt];
            out[base + lane + 64] = x[base + lane + 64] + a2[tt];
        }
    }
}

// ---------------- Kernel 3: LN2 + FC1 + GELU + FC2 + residual, 32 tokens/block ----------------
__global__ __launch_bounds__(256, 2) void k_mlp2(
    const float* __restrict__ g2v, const float* __restrict__ b2v,
    const float* __restrict__ w1,  const float* __restrict__ b1f,
    const float* __restrict__ w2,  const float* __restrict__ b2f,
    float* __restrict__ xio) {
    __shared__ __align__(16) float h2s[3200];   // [32][100]
    __shared__ __align__(16) float ys[12416];   // [32][388]
    const int tid = threadIdx.x, lane = tid & 31, sub = tid >> 5;
    const size_t base = (size_t)blockIdx.x * 32;
    // LN2
    for (int k = 0; k < 4; ++k) {
        int rl = sub + 8 * k;
        const float* row = xio + (base + rl) * 96;
        float v0 = row[lane], v1 = row[lane + 32], v2 = row[lane + 64];
        float s = v0 + v1 + v2, s2 = v0 * v0 + v1 * v1 + v2 * v2;
        #pragma unroll
        for (int off = 16; off >= 1; off >>= 1) {
            s  += __shfl_xor(s,  off, 32);
            s2 += __shfl_xor(s2, off, 32);
        }
        float mu = s * (1.f / 96.f);
        float rs = rsqrtf(s2 * (1.f / 96.f) - mu * mu + 1e-5f);
        h2s[rl * 100 + lane]      = (v0 - mu) * rs * g2v[lane]      + b2v[lane];
        h2s[rl * 100 + lane + 32] = (v1 - mu) * rs * g2v[lane + 32] + b2v[lane + 32];
        h2s[rl * 100 + lane + 64] = (v2 - mu) * rs * g2v[lane + 64] + b2v[lane + 64];
    }
    __syncthreads();
    // FC1 + exact GELU
    for (int jt = 0; jt < 4; ++jt) {
        int j0 = jt * 96 + lane, j1 = j0 + 32, j2 = j0 + 64;
        float a0[4], a1[4], a2[4];
        #pragma unroll
        for (int k = 0; k < 4; ++k) { a0[k] = b1f[j0]; a1[k] = b1f[j1]; a2[k] = b1f[j2]; }
        for (int cc = 0; cc < 24; ++cc) {
            int c = cc * 4;
            const float* wb = w1 + (size_t)c * 384;
            float w00 = wb[j0], w01 = wb[384 + j0], w02 = wb[768 + j0], w03 = wb[1152 + j0];
            float w10 = wb[j1], w11 = wb[384 + j1], w12 = wb[768 + j1], w13 = wb[1152 + j1];
            float w20 = wb[j2], w21 = wb[384 + j2], w22 = wb[768 + j2], w23 = wb[1152 + j2];
            #pragma unroll
            for (int k = 0; k < 4; ++k) {
                float4 hv = *reinterpret_cast<const float4*>(&h2s[(sub + 8 * k) * 100 + c]);
                a0[k] += hv.x * w00 + hv.y * w01 + hv.z * w02 + hv.w * w03;
                a1[k] += hv.x * w10 + hv.y * w11 + hv.z * w12 + hv.w * w13;
                a2[k] += hv.x * w20 + hv.y * w21 + hv.z * w22 + hv.w * w23;
            }
        }
        #pragma unroll
        for (int k = 0; k < 4; ++k) {
            int rl = sub + 8 * k;
            ys[rl * 388 + j0] = gelu_exact(a0[k]);
            ys[rl * 388 + j1] = gelu_exact(a1[k]);
            ys[rl * 388 + j2] = gelu_exact(a2[k]);
        }
    }
    __syncthreads();
    // FC2 + residual
    {
        float a0[4], a1[4], a2[4];
        const float bb0 = b2f[lane], bb1 = b2f[lane + 32], bb2 = b2f[lane + 64];
        #pragma unroll
        for (int k = 0; k < 4; ++k) { a0[k] = bb0; a1[k] = bb1; a2[k] = bb2; }
        for (int jc = 0; jc < 96; ++jc) {
            int j = jc * 4;
            const float* wb = w2 + (size_t)j * 96;
            float w00 = wb[lane],      w01 = wb[96 + lane],  w02 = wb[192 + lane], w03 = wb[288 + lane];
            float w10 = wb[32 + lane], w11 = wb[128 + lane], w12 = wb[224 + lane], w13 = wb[320 + lane];
            float w20 = wb[64 + lane], w21 = wb[160 + lane], w22 = wb[256 + lane], w23 = wb[352 + lane];
            #pragma unroll
            for (int k = 0; k < 4; ++k) {
                float4 yv = *reinterpret_cast<const float4*>(&ys[(sub + 8 * k) * 388 + j]);
                a0[k] += yv.x * w00 + yv.y * w01 + yv.z * w02 + yv.w * w03;
                a1[k] += yv.x * w10 + yv.y * w11 + yv.z * w12 + yv.w * w13;
                a2[k] += yv.x * w20 + yv.y * w21 + yv.z * w22 + yv.w * w23;
            }
        }
        #pragma unroll
        for (int k = 0; k < 4; ++k) {
            float* row = xio + (base + sub + 8 * k) * 96;
            row[lane]      += a0[k];
            row[lane + 32] += a1[k];
            row[lane + 64] += a2[k];
        }
    }
}

extern "C" void kernel_launch(void* const* d_in, const int* in_sizes, int n_in,
                              void* d_out, int out_size, void* d_ws, size_t ws_size,
                              hipStream_t stream) {
    const float* x      = (const float*)d_in[0];
    const float* mask   = (const float*)d_in[1];
    const float* g1     = (const float*)d_in[2];
    const float* b1     = (const float*)d_in[3];
    const float* w_qkv  = (const float*)d_in[4];
    const float* b_qkv  = (const float*)d_in[5];
    const float* w_proj = (const float*)d_in[6];
    const float* b_proj = (const float*)d_in[7];
    const float* btab   = (const float*)d_in[8];
    const int*   relidx = (const int*)d_in[9];
    const float* g2     = (const float*)d_in[10];
    const float* b2     = (const float*)d_in[11];
    const float* w_fc1  = (const float*)d_in[12];
    const float* b_fc1  = (const float*)d_in[13];
    const float* w_fc2  = (const float*)d_in[14];
    const float* b_fc2  = (const float*)d_in[15];
    float* out  = (float*)d_out;
    float* obuf = (float*)d_ws;   // 4096*98*96 fp32 = 154,140,672 B

    hipLaunchKernelGGL(k_attn2, dim3(12288), dim3(256), 0, stream,
                       x, mask, g1, b1, w_qkv, b_qkv, btab, relidx, obuf);
    hipLaunchKernelGGL(k_proj, dim3(4096), dim3(256), 0, stream,
                       obuf, x, w_proj, b_proj, out);
    hipLaunchKernelGGL(k_mlp2, dim3(401408 / 32), dim3(256), 0, stream,
                       g2, b2, w_fc1, b_fc1, w_fc2, b_fc2, out);
}

// Round 3
// 1088.505 us; speedup vs baseline: 12.9441x; 4.7865x over previous
//
#include <hip/hip_runtime.h>
#include <hip/hip_bf16.h>

typedef _Float16 f16x4 __attribute__((ext_vector_type(4)));
typedef float f32x16 __attribute__((ext_vector_type(16)));

#define SCALE_Q 0.17677669529663687f

// ---------- ws layout (bytes) ----------
#define OBUF_OFF   0ull                    // f16 [4096][98][96] = 77,070,336 B
#define WQKVT_OFF  77070336ull             // f16 [288][96]
#define WPT_OFF    77125632ull             // f16 [96][96]
#define W1T_OFF    77144064ull             // f16 [384][96]
#define W2T_OFF    77217792ull             // f16 [96][384]
#define BIASB_OFF  77291520ull             // f32 [3][98][98]

// ---------------- prep: transpose weights to f16 [N][K], build bias table ----------------
__global__ __launch_bounds__(256, 4) void k_prep(
    const float* __restrict__ w_qkv, const float* __restrict__ w_proj,
    const float* __restrict__ w_fc1, const float* __restrict__ w_fc2,
    const float* __restrict__ btab, const int* __restrict__ relidx,
    char* __restrict__ ws) {
    _Float16* wqkvT = (_Float16*)(ws + WQKVT_OFF);
    _Float16* wpT   = (_Float16*)(ws + WPT_OFF);
    _Float16* w1T   = (_Float16*)(ws + W1T_OFF);
    _Float16* w2T   = (_Float16*)(ws + W2T_OFF);
    float*    biasb = (float*)(ws + BIASB_OFF);
    int e = blockIdx.x * 256 + threadIdx.x;
    if (e < 27648) {                       // wqkvT[col][c] = w_qkv[c][col]
        int col = e / 96, c = e - col * 96;
        wqkvT[e] = (_Float16)w_qkv[c * 288 + col];
    } else if (e < 27648 + 9216) {         // wpT[n][k] = w_proj[k][n]
        int r = e - 27648; int nn = r / 96, k = r - nn * 96;
        wpT[r] = (_Float16)w_proj[k * 96 + nn];
    } else if (e < 36864 + 36864) {        // w1T[n][k] = w_fc1[k][n]   (n<384,k<96)
        int r = e - 36864; int nn = r / 96, k = r - nn * 96;
        w1T[r] = (_Float16)w_fc1[k * 384 + nn];
    } else if (e < 73728 + 36864) {        // w2T[n][k] = w_fc2[k][n]   (n<96,k<384)
        int r = e - 73728; int nn = r / 384, k = r - nn * 384;
        w2T[r] = (_Float16)w_fc2[k * 96 + nn];
    } else if (e < 110592 + 28812) {       // biasb[h][ij] = btab[relidx[ij]*3+h]
        int r = e - 110592; int hh = r / 9604, ij = r - hh * 9604;
        biasb[r] = btab[relidx[ij] * 3 + hh];
    }
}

// region label along one axis helper lives inline below.

// ---------------- attention: one block per (window, head) ----------------
// LDS: Qs f16[128][36] | Ks f16[128][36] | VTs f16[32][108] | Ps f16[128][108] (aliased as xw[128][100]) | labL[128]
__global__ __launch_bounds__(256, 3) void k_attn3(
    const float* __restrict__ x,
    const float* __restrict__ g1v, const float* __restrict__ b1v,
    const float* __restrict__ b_qkv,
    const char* __restrict__ ws_ro,
    char* __restrict__ ws) {
    __shared__ _Float16 Qs[128 * 36];
    __shared__ _Float16 Ks[128 * 36];
    __shared__ _Float16 VTs[32 * 108];
    __shared__ _Float16 Ps[128 * 108];
    __shared__ unsigned char labL[128];
    _Float16* xw = Ps;                     // [128][100], dead after QKV

    const _Float16* wqkvT = (const _Float16*)(ws_ro + WQKVT_OFF);
    const float*    biasb = (const float*)(ws_ro + BIASB_OFF);
    _Float16*       obuf  = (_Float16*)(ws + OBUF_OFF);

    const int tid = threadIdx.x;
    const int bid = blockIdx.x;
    const int w = bid / 3;
    const int h = bid - 3 * w;
    const int b = w >> 9;
    const int nwi = w & 511;
    const int dq = nwi >> 6, hq = (nwi >> 3) & 7, wq = nwi & 7;

    // labels for mask (shifted-grid coords)
    if (tid < 128) {
        int t = tid;
        unsigned char lv;
        if (t < 98) {
            int td = t / 49; int r = t - td * 49; int th = r / 7; int tw = r - th * 7;
            int d0 = dq * 2 + td;
            int h0 = hq * 7 + th;
            int w0 = wq * 7 + tw;
            int ld = (d0 < 14) ? 0 : ((d0 < 15) ? 1 : 2);
            int lh = (h0 < 49) ? 0 : ((h0 < 53) ? 1 : 2);
            int lw = (w0 < 49) ? 0 : ((w0 < 53) ? 1 : 2);
            lv = (unsigned char)((ld * 3 + lh) * 3 + lw);
        } else lv = (unsigned char)(100 + t);
        labL[t] = lv;
    }
    // zero V-transpose tail columns (tokens 98..107) to block NaN propagation
    for (int e = tid; e < 320; e += 256) {
        int nn = e / 10, cc = 98 + (e - nn * 10);
        VTs[nn * 108 + cc] = (_Float16)0.f;
    }
    // ---- LN1 + cyclic shift gather -> xw (f16) ----
    {
        const int lane = tid & 31, sub = tid >> 5;
        for (int it = 0; it < 13; ++it) {
            int t = sub + 8 * it;
            if (t < 98) {
                int td = t / 49; int r = t - td * 49; int th = r / 7; int tw = r - th * 7;
                int gd = (dq * 2 + td + 1) & 15;
                int gh = hq * 7 + th + 3; if (gh >= 56) gh -= 56;
                int gw = wq * 7 + tw + 3; if (gw >= 56) gw -= 56;
                const float* row = x + (size_t)(((b * 16 + gd) * 56 + gh) * 56 + gw) * 96;
                float v0 = row[lane], v1 = row[lane + 32], v2 = row[lane + 64];
                float s = v0 + v1 + v2, s2 = v0 * v0 + v1 * v1 + v2 * v2;
                #pragma unroll
                for (int off = 16; off >= 1; off >>= 1) {
                    s  += __shfl_xor(s,  off, 32);
                    s2 += __shfl_xor(s2, off, 32);
                }
                float mu = s * (1.f / 96.f);
                float rs = rsqrtf(s2 * (1.f / 96.f) - mu * mu + 1e-5f);
                xw[t * 100 + lane]      = (_Float16)((v0 - mu) * rs * g1v[lane]      + b1v[lane]);
                xw[t * 100 + lane + 32] = (_Float16)((v1 - mu) * rs * g1v[lane + 32] + b1v[lane + 32]);
                xw[t * 100 + lane + 64] = (_Float16)((v2 - mu) * rs * g1v[lane + 64] + b1v[lane + 64]);
            }
        }
    }
    __syncthreads();

    const int l  = tid & 63;
    const int wid = tid >> 6;
    const int n  = l & 31;
    const int hi = l >> 5;
    const int mtb = wid * 32;

    // ---- QKV (MFMA): A = xw rows, B = wqkvT cols ----
    {
        f16x4 af[12];
        #pragma unroll
        for (int ks = 0; ks < 12; ++ks)
            af[ks] = *reinterpret_cast<const f16x4*>(&xw[(mtb + n) * 100 + 8 * ks + 4 * hi]);
        #pragma unroll
        for (int sel = 0; sel < 3; ++sel) {
            int col = sel * 96 + h * 32 + n;
            float bias = b_qkv[col];
            f32x16 acc;
            #pragma unroll
            for (int r2 = 0; r2 < 16; ++r2) acc[r2] = bias;
            #pragma unroll
            for (int ks = 0; ks < 12; ++ks) {
                f16x4 bf = *reinterpret_cast<const f16x4*>(wqkvT + (size_t)col * 96 + 8 * ks + 4 * hi);
                acc = __builtin_amdgcn_mfma_f32_32x32x8f16(af[ks], bf, acc, 0, 0, 0);
            }
            #pragma unroll
            for (int rg = 0; rg < 16; ++rg) {
                int r2 = mtb + (rg & 3) + 8 * (rg >> 2) + 4 * hi;
                float v = acc[rg];
                if (sel == 0) {
                    Qs[r2 * 36 + n] = (_Float16)(v * SCALE_Q);
                } else if (sel == 1) {
                    Ks[r2 * 36 + n] = (_Float16)v;
                } else {
                    if (r2 < 98) VTs[n * 108 + r2] = (_Float16)v;
                }
            }
        }
    }
    __syncthreads();

    // ---- S = q@k^T (MFMA) + bias + mask, softmax in registers -> Ps ----
    {
        f16x4 aq[4];
        #pragma unroll
        for (int ks = 0; ks < 4; ++ks)
            aq[ks] = *reinterpret_cast<const f16x4*>(&Qs[(mtb + n) * 36 + 8 * ks + 4 * hi]);
        f32x16 sc[4];
        #pragma unroll
        for (int nt = 0; nt < 4; ++nt) {
            f32x16 a;
            #pragma unroll
            for (int r2 = 0; r2 < 16; ++r2) a[r2] = 0.f;
            #pragma unroll
            for (int ks = 0; ks < 4; ++ks) {
                f16x4 bf = *reinterpret_cast<const f16x4*>(&Ks[(nt * 32 + n) * 36 + 8 * ks + 4 * hi]);
                a = __builtin_amdgcn_mfma_f32_32x32x8f16(aq[ks], bf, a, 0, 0, 0);
            }
            sc[nt] = a;
        }
        unsigned char lj[4];
        #pragma unroll
        for (int nt = 0; nt < 4; ++nt) lj[nt] = labL[nt * 32 + n];
        const float* bb = biasb + (size_t)h * 9604;
        #pragma unroll
        for (int rg = 0; rg < 16; ++rg) {
            int i = mtb + (rg & 3) + 8 * (rg >> 2) + 4 * hi;
            unsigned char li = labL[i];
            float m = -1e30f;
            #pragma unroll
            for (int nt = 0; nt < 4; ++nt) {
                int j = nt * 32 + n;
                float s;
                if (i < 98 && j < 98) {
                    s = sc[nt][rg] + bb[i * 98 + j] + ((li != lj[nt]) ? -100.f : 0.f);
                } else {
                    s = -1e30f;
                }
                sc[nt][rg] = s;
                m = fmaxf(m, s);
            }
            #pragma unroll
            for (int off = 1; off <= 16; off <<= 1) m = fmaxf(m, __shfl_xor(m, off));
            float ssum = 0.f;
            #pragma unroll
            for (int nt = 0; nt < 4; ++nt) {
                float p = __expf(sc[nt][rg] - m);
                sc[nt][rg] = p;
                ssum += p;
            }
            #pragma unroll
            for (int off = 1; off <= 16; off <<= 1) ssum += __shfl_xor(ssum, off);
            float inv = 1.f / ssum;
            #pragma unroll
            for (int nt = 0; nt < 4; ++nt) {
                int j = nt * 32 + n;
                if (j < 104) Ps[i * 108 + j] = (_Float16)(sc[nt][rg] * inv);
            }
        }
    }
    __syncthreads();

    // ---- O = P @ V (MFMA) -> obuf f16 ----
    {
        f32x16 acc;
        #pragma unroll
        for (int r2 = 0; r2 < 16; ++r2) acc[r2] = 0.f;
        #pragma unroll
        for (int ks = 0; ks < 13; ++ks) {
            f16x4 ap = *reinterpret_cast<const f16x4*>(&Ps[(mtb + n) * 108 + 8 * ks + 4 * hi]);
            f16x4 bv = *reinterpret_cast<const f16x4*>(&VTs[n * 108 + 8 * ks + 4 * hi]);
            acc = __builtin_amdgcn_mfma_f32_32x32x8f16(ap, bv, acc, 0, 0, 0);
        }
        #pragma unroll
        for (int rg = 0; rg < 16; ++rg) {
            int t = mtb + (rg & 3) + 8 * (rg >> 2) + 4 * hi;
            if (t < 98) obuf[((size_t)w * 98 + t) * 96 + h * 32 + n] = (_Float16)acc[rg];
        }
    }
}

// ---------------- proj + shortcut + reverse-shift scatter (pure register MFMA) ----------------
__global__ __launch_bounds__(256, 4) void k_proj3(
    const char* __restrict__ ws_ro,
    const float* __restrict__ x,
    const float* __restrict__ b_proj,
    float* __restrict__ out) {
    const _Float16* obuf = (const _Float16*)(ws_ro + OBUF_OFF);
    const _Float16* wpT  = (const _Float16*)(ws_ro + WPT_OFF);
    const int tid = threadIdx.x;
    const int w = blockIdx.x;
    const int l = tid & 63, wid = tid >> 6, n = l & 31, hi = l >> 5;
    const int mtb = wid * 32;
    f16x4 af[12];
    {
        int t = mtb + n; int tr = (t < 98) ? t : 97;
        #pragma unroll
        for (int ks = 0; ks < 12; ++ks)
            af[ks] = *reinterpret_cast<const f16x4*>(obuf + ((size_t)w * 98 + tr) * 96 + 8 * ks + 4 * hi);
    }
    f32x16 accs[3];
    #pragma unroll
    for (int nt = 0; nt < 3; ++nt) {
        int col = nt * 32 + n;
        float bias = b_proj[col];
        f32x16 a;
        #pragma unroll
        for (int r2 = 0; r2 < 16; ++r2) a[r2] = bias;
        #pragma unroll
        for (int ks = 0; ks < 12; ++ks) {
            f16x4 bf = *reinterpret_cast<const f16x4*>(wpT + (size_t)col * 96 + 8 * ks + 4 * hi);
            a = __builtin_amdgcn_mfma_f32_32x32x8f16(af[ks], bf, a, 0, 0, 0);
        }
        accs[nt] = a;
    }
    const int b = w >> 9, nwi = w & 511;
    const int dq = nwi >> 6, hq = (nwi >> 3) & 7, wq = nwi & 7;
    #pragma unroll
    for (int rg = 0; rg < 16; ++rg) {
        int t = mtb + (rg & 3) + 8 * (rg >> 2) + 4 * hi;
        if (t < 98) {
            int td = t / 49; int r = t - td * 49; int th = r / 7; int tw = r - th * 7;
            int gd = (dq * 2 + td + 1) & 15;
            int gh = hq * 7 + th + 3; if (gh >= 56) gh -= 56;
            int gw = wq * 7 + tw + 3; if (gw >= 56) gw -= 56;
            size_t base = (size_t)(((b * 16 + gd) * 56 + gh) * 56 + gw) * 96;
            #pragma unroll
            for (int nt = 0; nt < 3; ++nt) {
                int col = nt * 32 + n;
                out[base + col] = x[base + col] + accs[nt][rg];
            }
        }
    }
}

// ---------------- MLP: LN2 + FC1 + GELU + FC2 + residual, 64 tokens/block ----------------
__global__ __launch_bounds__(256, 2) void k_mlp3(
    const float* __restrict__ g2v, const float* __restrict__ b2v,
    const float* __restrict__ b_fc1, const float* __restrict__ b_fc2,
    const char* __restrict__ ws_ro,
    float* __restrict__ out) {
    __shared__ _Float16 xb[64 * 100];
    __shared__ _Float16 hb[64 * 388];
    const _Float16* w1T = (const _Float16*)(ws_ro + W1T_OFF);
    const _Float16* w2T = (const _Float16*)(ws_ro + W2T_OFF);
    const int tid = threadIdx.x;
    const size_t tokBase = (size_t)blockIdx.x * 64;
    // LN2
    {
        const int lane = tid & 31, sub = tid >> 5;
        for (int it = 0; it < 8; ++it) {
            int rt = sub + 8 * it;
            const float* row = out + (tokBase + rt) * 96;
            float v0 = row[lane], v1 = row[lane + 32], v2 = row[lane + 64];
            float s = v0 + v1 + v2, s2 = v0 * v0 + v1 * v1 + v2 * v2;
            #pragma unroll
            for (int off = 16; off >= 1; off >>= 1) {
                s  += __shfl_xor(s,  off, 32);
                s2 += __shfl_xor(s2, off, 32);
            }
            float mu = s * (1.f / 96.f);
            float rs = rsqrtf(s2 * (1.f / 96.f) - mu * mu + 1e-5f);
            xb[rt * 100 + lane]      = (_Float16)((v0 - mu) * rs * g2v[lane]      + b2v[lane]);
            xb[rt * 100 + lane + 32] = (_Float16)((v1 - mu) * rs * g2v[lane + 32] + b2v[lane + 32]);
            xb[rt * 100 + lane + 64] = (_Float16)((v2 - mu) * rs * g2v[lane + 64] + b2v[lane + 64]);
        }
    }
    __syncthreads();
    const int l = tid & 63, wid = tid >> 6, n = l & 31, hi = l >> 5;
    // FC1 + GELU -> hb
    {
        const int mt = wid & 1;
        const int nt0 = wid >> 1;
        f16x4 af[12];
        #pragma unroll
        for (int ks = 0; ks < 12; ++ks)
            af[ks] = *reinterpret_cast<const f16x4*>(&xb[(mt * 32 + n) * 100 + 8 * ks + 4 * hi]);
        for (int s6 = 0; s6 < 6; ++s6) {
            int nt = nt0 + 2 * s6;
            int col = nt * 32 + n;
            float bias = b_fc1[col];
            f32x16 acc;
            #pragma unroll
            for (int r2 = 0; r2 < 16; ++r2) acc[r2] = bias;
            #pragma unroll
            for (int ks = 0; ks < 12; ++ks) {
                f16x4 bf = *reinterpret_cast<const f16x4*>(w1T + (size_t)col * 96 + 8 * ks + 4 * hi);
                acc = __builtin_amdgcn_mfma_f32_32x32x8f16(af[ks], bf, acc, 0, 0, 0);
            }
            #pragma unroll
            for (int rg = 0; rg < 16; ++rg) {
                int r2 = mt * 32 + (rg & 3) + 8 * (rg >> 2) + 4 * hi;
                float v = acc[rg];
                float g = 0.5f * v * (1.f + erff(v * 0.70710678118654752f));
                hb[r2 * 388 + col] = (_Float16)g;
            }
        }
    }
    __syncthreads();
    // FC2 + residual
    for (int u = wid; u < 6; u += 4) {
        int nt = u >> 1, mt = u & 1;
        int col = nt * 32 + n;
        float bias = b_fc2[col];
        f32x16 acc;
        #pragma unroll
        for (int r2 = 0; r2 < 16; ++r2) acc[r2] = bias;
        #pragma unroll
        for (int ks = 0; ks < 48; ++ks) {
            f16x4 ah = *reinterpret_cast<const f16x4*>(&hb[(mt * 32 + n) * 388 + 8 * ks + 4 * hi]);
            f16x4 bf = *reinterpret_cast<const f16x4*>(w2T + (size_t)col * 384 + 8 * ks + 4 * hi);
            acc = __builtin_amdgcn_mfma_f32_32x32x8f16(ah, bf, acc, 0, 0, 0);
        }
        #pragma unroll
        for (int rg = 0; rg < 16; ++rg) {
            int t = mt * 32 + (rg & 3) + 8 * (rg >> 2) + 4 * hi;
            size_t idx = (tokBase + t) * 96 + col;
            out[idx] = out[idx] + acc[rg];
        }
    }
}

extern "C" void kernel_launch(void* const* d_in, const int* in_sizes, int n_in,
                              void* d_out, int out_size, void* d_ws, size_t ws_size,
                              hipStream_t stream) {
    const float* x      = (const float*)d_in[0];
    const float* g1     = (const float*)d_in[2];
    const float* b1     = (const float*)d_in[3];
    const float* w_qkv  = (const float*)d_in[4];
    const float* b_qkv  = (const float*)d_in[5];
    const float* w_proj = (const float*)d_in[6];
    const float* b_proj = (const float*)d_in[7];
    const float* btab   = (const float*)d_in[8];
    const int*   relidx = (const int*)d_in[9];
    const float* g2     = (const float*)d_in[10];
    const float* b2     = (const float*)d_in[11];
    const float* w_fc1  = (const float*)d_in[12];
    const float* b_fc1  = (const float*)d_in[13];
    const float* w_fc2  = (const float*)d_in[14];
    const float* b_fc2  = (const float*)d_in[15];
    float* out = (float*)d_out;
    char*  ws  = (char*)d_ws;

    hipLaunchKernelGGL(k_prep, dim3(545), dim3(256), 0, stream,
                       w_qkv, w_proj, w_fc1, w_fc2, btab, relidx, ws);
    hipLaunchKernelGGL(k_attn3, dim3(12288), dim3(256), 0, stream,
                       x, g1, b1, b_qkv, (const char*)ws, ws);
    hipLaunchKernelGGL(k_proj3, dim3(4096), dim3(256), 0, stream,
                       (const char*)ws, x, b_proj, out);
    hipLaunchKernelGGL(k_mlp3, dim3(401408 / 64), dim3(256), 0, stream,
                       g2, b2, b_fc1, b_fc2, (const char*)ws, out);
}